// Round 9
// baseline (182.048 us; speedup 1.0000x reference)
//
#include <hip/hip_runtime.h>
#include <math.h>

#define KNN 16
#define NPTS 8192
#define PTCH 256
#define NPATCH 32
#define NBATCH 4
#define NQ 16            // queries per block (sixteenth patch)
#define TILE 1024        // candidates per LDS tile
#define SSTRIDE 130      // survivor slots/query (mean 64, +8sigma)
#define LAMBDA_T 64.0f   // target E[survivors]/query

// E[#points within distance s of a query at radius r], N iid N(0,I3). fp32.
// Heuristic only: exactness guaranteed by phase-B margin check + fallback.
__device__ __forceinline__ float lam_f(float r, float s)
{
    const float C     = 0.063493636f;    // (2*pi)^{-3/2}
    const float SQ2PI = 2.5066283f;
    const float IS2   = 0.70710678f;
    float a = fabsf(r - s), b = r + s;
    float amr = a - r;
    float coefA = amr * amr + 2.f - s * s;   // == 2 when r >= s (R5 bug fixed)
    float I = 2.f * __expf(-0.5f * b * b) - coefA * __expf(-0.5f * a * a)
            + r * SQ2PI * (erff(b * IS2) - erff(a * IS2));
    float M = C * (3.14159265f / r) * I;
    if (s > r) {
        float u = s - r;
        M += 12.566371f * C * (1.2533141f * erff(u * IS2) - u * __expf(-0.5f * u * u));
    }
    return (float)NPTS * M;
}

// ---------- fp32 cyclic Jacobi 3x3 (ported from R1-R8-verified fp64 version) ----------
__device__ __forceinline__ void jrotf(float& app, float& aqq, float& apq,
                                      float& arp, float& arq,
                                      float& vp0, float& vq0,
                                      float& vp1, float& vq1,
                                      float& vp2, float& vq2)
{
    float g = apq;
    if (g == 0.f) return;
    float theta = (aqq - app) / (2.f * g);
    float at = fabsf(theta);
    float t = (at > 1.0e18f) ? (0.5f / theta)
                             : (copysignf(1.f, theta) / (at + sqrtf(theta * theta + 1.f)));
    float c = 1.f / sqrtf(t * t + 1.f);
    float s = t * c;
    float tau = s / (1.f + c);
    app -= t * g;
    aqq += t * g;
    apq = 0.f;
    float rp = arp, rq = arq;
    arp = rp - s * (rq + tau * rp);
    arq = rq + s * (rp - tau * rq);
    float p0 = vp0, q0 = vq0;
    vp0 = p0 - s * (q0 + tau * p0); vq0 = q0 + s * (p0 - tau * q0);
    float p1 = vp1, q1 = vq1;
    vp1 = p1 - s * (q1 + tau * p1); vq1 = q1 + s * (p1 - tau * q1);
    float p2 = vp2, q2 = vq2;
    vp2 = p2 - s * (q2 + tau * p2); vq2 = q2 + s * (p2 - tau * q2);
}

__device__ __forceinline__ void eig3f(float a00, float a11, float a22,
                                      float a01, float a02, float a12,
                                      float& nx, float& ny, float& nz,
                                      float& lmin, float& lsum)
{
    float v00 = 1, v01 = 0, v02 = 0;
    float v10 = 0, v11 = 1, v12 = 0;
    float v20 = 0, v21 = 0, v22 = 1;
    float scale = fabsf(a00) + fabsf(a11) + fabsf(a22) + fabsf(a01) + fabsf(a02) + fabsf(a12);
    if (scale > 0.f) {
        for (int sweep = 0; sweep < 6; ++sweep) {
            float off = fabsf(a01) + fabsf(a02) + fabsf(a12);
            if (off <= scale * 1e-7f) break;
            jrotf(a00, a11, a01, a02, a12, v00, v01, v10, v11, v20, v21);
            jrotf(a00, a22, a02, a01, a12, v00, v02, v10, v12, v20, v22);
            jrotf(a11, a22, a12, a01, a02, v01, v02, v11, v12, v21, v22);
        }
    }
    lsum = a00 + a11 + a22;
    lmin = a00; nx = v00; ny = v10; nz = v20;
    if (a11 < lmin) { lmin = a11; nx = v01; ny = v11; nz = v21; }
    if (a22 < lmin) { lmin = a22; nx = v02; ny = v12; nz = v22; }
}

// u32 key: (d2 float bits, low 13 mantissa bits cleared) | idx(13b). Ties -> lower idx.
__device__ __forceinline__ unsigned mkkey(float d2, unsigned idx) {
    return (__float_as_uint(d2) & 0xFFFFE000u) | idx;
}

// Caller guarantees key < L[15]. Sorted-ascending bubble (v_min/v_max pairs).
__device__ __forceinline__ void insert16(unsigned key, unsigned* L)
{
    L[KNN - 1] = key;
    #pragma unroll
    for (int m = KNN - 1; m >= 1; --m) {
        unsigned a = L[m - 1], b = L[m];
        L[m - 1] = min(a, b);
        L[m]     = max(a, b);
    }
}

// Snapshot-based butterfly merge of sorted 16-lists across 8-lane groups
// (steps 1,2,4). Snapshot happens before inserts so both partners see the
// pre-merge lists; afterwards all 8 lanes hold the merged top-16.
__device__ __forceinline__ void merge8(unsigned* L, int lane)
{
    #pragma unroll
    for (int step = 1; step <= 4; step <<= 1) {
        unsigned tmp[KNN];
        #pragma unroll
        for (int m = 0; m < KNN; ++m) tmp[m] = __shfl(L[m], lane ^ step, 64);
        for (int m = 0; m < KNN; ++m) {
            if (tmp[m] >= L[KNN - 1]) break;
            insert16(tmp[m], L);
        }
    }
}

__device__ __forceinline__ float rfl(float x) {
    return __int_as_float(__builtin_amdgcn_readfirstlane(__float_as_int(x)));
}
__device__ __forceinline__ unsigned mbcnt64(unsigned long long m) {
    return __builtin_amdgcn_mbcnt_hi((unsigned)(m >> 32),
           __builtin_amdgcn_mbcnt_lo((unsigned)m, 0u));
}

// Block = 256 threads, 16 queries (sixteenth patch); grid 2048 -> 6 blocks/CU (LDS).
// Phase A: each wave ballot-filters all 8192 candidates against its 4 queries.
// Phase B: waves0/1 = global top-16 (8 lanes/query) + fp32 cov/eig;
//          waves2/3 = patch kNN (8 lanes/query x 32 pts) + fp32 cov/eig.
__global__ void __launch_bounds__(256, 6)
spl_main(const float* __restrict__ pts, float* __restrict__ out)
{
    __shared__ float4 tile4[TILE];                 // 16 KB candidate tile
    __shared__ float4 pbuf4[PTCH];                 // 4 KB own patch
    __shared__ unsigned short surv[NQ * SSTRIDE];  // 4.1 KB survivor indices
    __shared__ unsigned cnts[NQ];
    __shared__ float gbuf[NQ];
    __shared__ float xbuf[NQ * 4];                 // patch normal+sv (fp32)
    __shared__ double rb[4];
    // ~25 KB -> 6 blocks/CU

    const int t = threadIdx.x;
    const int w = t >> 6;
    const int lane = t & 63;
    const int p = blockIdx.x;
    const int six = blockIdx.y;    // sixteenth of the patch
    const int b = blockIdx.z;

    const float* base = pts + (size_t)b * (NPTS * 3);

    // Stage own patch into padded LDS.
    {
        const float* src = base + p * (PTCH * 3);
        float* dst = (float*)pbuf4;
        #pragma unroll
        for (int s = 0; s < 3; ++s) {
            int f = t + s * 256;
            int j = f / 3;
            int c = f - 3 * j;
            dst[j * 4 + c] = src[f];
        }
    }
    // Gates for this block's 16 queries (fp32 bisection, threads 0..15).
    if (t < NQ) {
        int qi = p * PTCH + six * NQ + t;
        float x = base[qi * 3 + 0], y = base[qi * 3 + 1], z = base[qi * 3 + 2];
        float r = fmaxf(sqrtf(x * x + y * y + z * z), 0.01f);
        float lo = 0.f, hi = 12.f;
        #pragma unroll 1
        for (int it = 0; it < 16; ++it) {
            float mid = 0.5f * (lo + hi);
            if (lam_f(r, mid) < LAMBDA_T) lo = mid; else hi = mid;
        }
        gbuf[t] = hi * hi;
    }
    __syncthreads();

    // This wave's 4 filter-queries: wave-uniform coords + thresholds in SGPRs.
    float sqx[4], sqy[4], sqz[4], shq[4];
    unsigned scnt[4];
    #pragma unroll
    for (int u = 0; u < 4; ++u) {
        float4 qv = pbuf4[six * NQ + w * 4 + u];
        float gg = gbuf[w * 4 + u];
        sqx[u] = rfl(qv.x); sqy[u] = rfl(qv.y); sqz[u] = rfl(qv.z);
        shq[u] = rfl(0.5f * (gg - (qv.x * qv.x + qv.y * qv.y + qv.z * qv.z)));
        scnt[u] = 0;
    }

    // ---- Phase A: ballot-compacted gate filter ----
    #pragma unroll 1
    for (int tb = 0; tb < NPTS; tb += TILE) {
        __syncthreads();
        {
            const float* src = base + tb * 3;
            float* dst = (float*)tile4;
            #pragma unroll
            for (int s = 0; s < 12; ++s) {
                int f = t + s * 256;
                int j = f / 3;
                int c = f - 3 * j;
                dst[j * 4 + c] = src[f];
            }
        }
        __syncthreads();
        float4 c = tile4[lane];
        #pragma unroll 1
        for (int it = 0; it < TILE / 64; ++it) {
            float4 cn = tile4[min(it + 1, TILE / 64 - 1) * 64 + lane];  // prefetch
            float hn = 0.5f * (c.x * c.x + c.y * c.y + c.z * c.z);
            unsigned gidx = (unsigned)(tb + it * 64 + lane);
            #pragma unroll
            for (int u = 0; u < 4; ++u) {
                // d2 < g  <=>  0.5|c|^2 - q.c < 0.5(g - |q|^2)
                float tt = fmaf(-c.x, sqx[u], hn);
                tt = fmaf(-c.y, sqy[u], tt);
                tt = fmaf(-c.z, sqz[u], tt);
                bool pass = tt < shq[u];
                unsigned long long m = __ballot(pass);
                if (m) {
                    unsigned pre = mbcnt64(m);
                    if (pass) {
                        unsigned slot = min(scnt[u] + pre, (unsigned)(SSTRIDE - 1));
                        surv[(w * 4 + u) * SSTRIDE + slot] = (unsigned short)gidx;
                    }
                    scnt[u] += (unsigned)__popcll(m);  // wave-uniform (SGPR)
                }
            }
            c = cn;
        }
    }
    if (lane == 0) {
        #pragma unroll
        for (int u = 0; u < 4; ++u) cnts[w * 4 + u] = scnt[u];
    }
    __syncthreads();   // B1

    // ---- Phase B: 8 lanes per query ----
    const int qq = lane >> 3;           // query within half 0..7
    const int h = lane & 7;             // sub-lane
    const int myq = (w & 1) * 8 + qq;   // query 0..15
    float4 qv = pbuf4[six * NQ + myq];
    const float pqx = qv.x, pqy = qv.y, pqz = qv.z;

    float ngx = 0.f, ngy = 0.f, ngz = 0.f, svg = 0.f;

    if (w < 2) {
        // Global top-16: split survivors 8 ways, gated bubble, butterfly merge.
        unsigned gl[KNN];
        #pragma unroll
        for (int m = 0; m < KNN; ++m) gl[m] = 0xFFFFFFFFu;
        unsigned cnt = cnts[myq];
        bool valid = (cnt >= KNN) && (cnt <= SSTRIDE);
        if (valid) {
            unsigned share = (cnt + 7) >> 3;
            unsigned m0 = h * share;
            unsigned m1 = min(m0 + share, cnt);
            #pragma unroll 1
            for (unsigned m = m0; m < m1; ++m) {
                unsigned idx = surv[myq * SSTRIDE + m];
                float cx = base[idx * 3 + 0];
                float cy = base[idx * 3 + 1];
                float cz = base[idx * 3 + 2];
                float dx = pqx - cx, dy = pqy - cy, dz = pqz - cz;
                float d2 = dx * dx + dy * dy + dz * dz;   // reference-form d2
                unsigned k = mkkey(d2, idx);
                if (k < gl[KNN - 1]) insert16(k, gl);
            }
        }
        merge8(gl, lane);
        if (valid) {
            // margin check: all filtered-out points provably outside 16th bucket
            float g = gbuf[myq];
            float upper = __uint_as_float((gl[KNN - 1] & 0xFFFFE000u) + 0x2000u);
            valid = (upper < g * 0.999f - 1e-5f);
        }
        if (__any((h == 0 && !valid) ? 1 : 0)) {
            if (h == 0 && !valid) {   // exact fallback (P ~ 1e-9/query)
                #pragma unroll
                for (int m = 0; m < KNN; ++m) gl[m] = 0xFFFFFFFFu;
                #pragma unroll 1
                for (int i = 0; i < NPTS; ++i) {
                    float cx = base[i * 3 + 0];
                    float cy = base[i * 3 + 1];
                    float cz = base[i * 3 + 2];
                    float dx = pqx - cx, dy = pqy - cy, dz = pqz - cz;
                    float d2 = dx * dx + dy * dy + dz * dz;
                    unsigned k = mkkey(d2, (unsigned)i);
                    if (k < gl[KNN - 1]) insert16(k, gl);
                }
            }
        }
        if (h == 0) {
            float c00 = 0, c11 = 0, c22 = 0, c01 = 0, c02 = 0, c12 = 0;
            #pragma unroll
            for (int m = 0; m < KNN; ++m) {
                int idx = (int)(gl[m] & 0x1FFFu);
                float dx = base[idx * 3 + 0] - pqx;
                float dy = base[idx * 3 + 1] - pqy;
                float dz = base[idx * 3 + 2] - pqz;
                c00 += dx * dx; c11 += dy * dy; c22 += dz * dz;
                c01 += dx * dy; c02 += dx * dz; c12 += dy * dz;
            }
            float lmin, lsum;
            eig3f(c00, c11, c22, c01, c02, c12, ngx, ngy, ngz, lmin, lsum);
            svg = lmin / lsum;
        }
    } else {
        // Patch kNN: 8 lanes x 32 patch points, gated bubble, butterfly merge.
        unsigned pl[KNN];
        #pragma unroll
        for (int m = 0; m < KNN; ++m) pl[m] = 0xFFFFFFFFu;
        const int j0 = h * 32;
        #pragma unroll 1
        for (int j = j0; j < j0 + 32; ++j) {
            float4 c = pbuf4[j];
            float dx = pqx - c.x, dy = pqy - c.y, dz = pqz - c.z;
            float d2 = dx * dx + dy * dy + dz * dz;
            unsigned k = mkkey(d2, (unsigned)j);
            if (k < pl[KNN - 1]) insert16(k, pl);
        }
        merge8(pl, lane);
        if (h == 0) {
            float c00 = 0, c11 = 0, c22 = 0, c01 = 0, c02 = 0, c12 = 0;
            #pragma unroll
            for (int m = 0; m < KNN; ++m) {
                int idx = (int)(pl[m] & 0x1FFFu);
                float4 cpt = pbuf4[idx];
                float dx = cpt.x - pqx;
                float dy = cpt.y - pqy;
                float dz = cpt.z - pqz;
                c00 += dx * dx; c11 += dy * dy; c22 += dz * dz;
                c01 += dx * dy; c02 += dx * dz; c12 += dy * dz;
            }
            float nx, ny, nz, lmin, lsum;
            eig3f(c00, c11, c22, c01, c02, c12, nx, ny, nz, lmin, lsum);
            xbuf[myq * 4 + 0] = nx;
            xbuf[myq * 4 + 1] = ny;
            xbuf[myq * 4 + 2] = nz;
            xbuf[myq * 4 + 3] = lmin / lsum;
        }
    }
    __syncthreads();   // B2

    double ln = 0.0, lsv = 0.0;
    if (w < 2) {
        if (h == 0) {
            double npx = xbuf[myq * 4 + 0];
            double npy = xbuf[myq * 4 + 1];
            double npz = xbuf[myq * 4 + 2];
            double svp = xbuf[myq * 4 + 3];
            double dx = fabs(npx) - fabs((double)ngx);
            double dy = fabs(npy) - fabs((double)ngy);
            double dz = fabs(npz) - fabs((double)ngz);
            ln  = sqrt(dx * dx + dy * dy + dz * dz);
            double ds = svp - (double)svg;
            lsv = ds * ds;
        }
        #pragma unroll
        for (int o = 32; o > 0; o >>= 1) {
            ln  += __shfl_down(ln, o);
            lsv += __shfl_down(lsv, o);
        }
        if (lane == 0) { rb[w * 2 + 0] = ln; rb[w * 2 + 1] = lsv; }
    }
    __syncthreads();   // B3
    if (t == 0) {
        const double inv = 1.0 / (double)(NBATCH * NPTS);
        atomicAdd(&out[0], (float)((rb[0] + rb[2]) * inv));
        atomicAdd(&out[1], (float)((rb[1] + rb[3]) * inv));
    }
}

extern "C" void kernel_launch(void* const* d_in, const int* in_sizes, int n_in,
                              void* d_out, int out_size, void* d_ws, size_t ws_size,
                              hipStream_t stream)
{
    const float* pts = (const float*)d_in[0];
    float* out = (float*)d_out;
    // async memset node (graph-capturable) instead of a zeroing kernel launch
    hipMemsetAsync(out, 0, 2 * sizeof(float), stream);
    dim3 grid(NPATCH, 16, NBATCH);
    hipLaunchKernelGGL(spl_main, grid, dim3(256), 0, stream, pts, out);
}